// Round 1
// baseline (725.143 us; speedup 1.0000x reference)
//
#include <hip/hip_runtime.h>
#include <hip/hip_bf16.h>

// ---- static problem geometry (from reference: IMAGE_SIZES // 14) ----
// hp x wp per image: (110,110)(80,110)(110,64)(56,90)(108,108)(110,80)(64,64)(90,110)
// token counts: 12100 8800 7040 5040 11664 8800 4096 9900  -> 67440
// merged (n/4): 3025 2200 1760 1260 2916 2200 1024 2475    -> 16860
#define MTOK  16860
#define NTOK  67440
#define NOUT  1024
#define KDIM  4096
#define NBM   132    // ceil(16860/128) -> padded M = 16896

__device__ __constant__ int c_mend[8] = {3025,5225,6985,8245,11161,13361,14385,16860};
__device__ __constant__ int c_moff[8] = {0,3025,5225,6985,8245,11161,13361,14385};
__device__ __constant__ int c_foff[8] = {0,12100,20900,27940,32980,44644,53444,57540};
__device__ __constant__ int c_wp[8]   = {110,110,64,90,108,80,64,110};

typedef __attribute__((ext_vector_type(8))) short          bf16x8;  // 8 bf16 = 4 VGPRs
typedef __attribute__((ext_vector_type(8))) unsigned short u16x8;
typedef __attribute__((ext_vector_type(4))) float          f32x4;

__device__ __forceinline__ unsigned short f2bf(float f) {
    unsigned int u = __float_as_uint(f);
    u += 0x7FFFu + ((u >> 16) & 1u);   // round-to-nearest-even
    return (unsigned short)(u >> 16);
}

__device__ __forceinline__ void async_copy16(const void* g, void* l) {
    __builtin_amdgcn_global_load_lds(
        (const __attribute__((address_space(1))) void*)g,
        (__attribute__((address_space(3))) void*)l, 16, 0, 0);
}

// ---- kernel 1: verbatim fp32 -> bf16 cast of feats (no reorder) ----
// 67440*1024 floats = 33720 blocks * 256 threads * 8 floats, exact.
__global__ __launch_bounds__(256) void cast_feats(const float* __restrict__ f,
                                                  unsigned short* __restrict__ o) {
    size_t g = ((size_t)blockIdx.x * 256 + threadIdx.x) * 8;
    float4 a = *(const float4*)(f + g);
    float4 b = *(const float4*)(f + g + 4);
    u16x8 v;
    v[0]=f2bf(a.x); v[1]=f2bf(a.y); v[2]=f2bf(a.z); v[3]=f2bf(a.w);
    v[4]=f2bf(b.x); v[5]=f2bf(b.y); v[6]=f2bf(b.z); v[7]=f2bf(b.w);
    *(u16x8*)(o + g) = v;
}

// ---- kernel 2: weight fp32 -> bf16 with K-permutation ----
// kappa' = c*1024 + d  (c = 2*ki+kj), so Wb[n][c*1024+d] = W[n][4d+c].
// Thread (n,d): one coalesced float4 read, 4 coalesced 2B writes (one per c-block).
__global__ __launch_bounds__(256) void cast_w_perm(const float* __restrict__ W,
                                                   unsigned short* __restrict__ Wb) {
    int g = blockIdx.x * 256 + threadIdx.x;   // 0 .. 1024*1024-1
    int n = g >> 10, d = g & 1023;
    float4 v = *(const float4*)(W + (size_t)n * 4096 + d * 4);
    unsigned short* o = Wb + (size_t)n * 4096 + d;
    o[0]    = f2bf(v.x);   // c=0 (ki=0,kj=0)
    o[1024] = f2bf(v.y);   // c=1 (ki=0,kj=1)
    o[2048] = f2bf(v.z);   // c=2 (ki=1,kj=0)
    o[3072] = f2bf(v.w);   // c=3 (ki=1,kj=1)
}

// ---- kernel 3: fused merge+GEMM. C[M,N] = A'[M,K'] * B'[N,K']^T ----
// A'[t][c*1024+d] = featsbf[frow(t,c)][d] gathered in-flight by the staging
// global_load_lds (per-lane source addresses; LDS dest stays linear).
// Single-barrier software pipeline + LDS dbuf, unchanged from prior version.
// XCD-chunked block swizzle: the 8 bn-siblings of each bm share one XCD's L2.
#define BM 128
#define BN 128
#define BK 32
__global__ __launch_bounds__(256) void gemm_fused(const unsigned short* __restrict__ A,
                                                  const unsigned short* __restrict__ B,
                                                  float* __restrict__ C) {
    __shared__ unsigned short lA[2][BM * BK];   // 2 x 8 KiB
    __shared__ unsigned short lB[2][BN * BK];   // 2 x 8 KiB

    // bijective XCD swizzle: grid = 1056 = 8 XCDs * 132 chunks
    const int orig    = blockIdx.y * 8 + blockIdx.x;
    const int logical = (orig & 7) * NBM + (orig >> 3);
    const int bn = logical & 7;          // 0..7
    const int bm = logical >> 3;         // 0..131

    const int tid  = threadIdx.x;
    const int wave = tid >> 6, lane = tid & 63;
    const int wm = (wave >> 1) * 64, wn = (wave & 1) * 64;

    const int lrow = lane >> 2;          // 0..15
    const int lcol = (lane & 3) * 8;     // 0,8,16,24 (bf16 elems)

    // per-thread A gather metadata: this thread stages rows chunk*16+lrow for
    // chunk = wave*2 + r. For each r: patch-row base and wp of its image.
    int abase[2], awp[2];
#pragma unroll
    for (int r = 0; r < 2; ++r) {
        int chunk = wave * 2 + r;
        int t = bm * BM + chunk * 16 + lrow;
        if (t >= MTOK) t = 0;            // pad rows: read valid garbage, store masked
        int im = 0;
        while (t >= c_mend[im]) im++;
        int rr  = t - c_moff[im];
        int wp  = c_wp[im];
        int wp2 = wp >> 1;
        int i = rr / wp2, j = rr - i * wp2;
        abase[r] = c_foff[im] + 2 * i * wp + 2 * j;   // feats row of patch (ki=0,kj=0)
        awp[r]   = wp;
    }

    const unsigned short* Bbase = B + (size_t)bn * BN * KDIM;

    f32x4 acc[4][4];
#pragma unroll
    for (int a = 0; a < 4; ++a)
#pragma unroll
        for (int b = 0; b < 4; ++b) acc[a][b] = (f32x4){0.f, 0.f, 0.f, 0.f};

    const int mrow = lane & 15;
    const int kq   = (lane >> 4) * 8;    // 0,8,16,24

    // prologue: stage k0=0 (c=0, d0=0) into buffer 0
#pragma unroll
    for (int r = 0; r < 2; ++r) {
        int chunk = wave * 2 + r;            // 0..7 (1 KiB LDS chunks)
        int row   = chunk * 16 + lrow;       // 0..127
        async_copy16(A + (((size_t)abase[r]) << 10) + lcol,
                     &lA[0][chunk * 512 + lane * 8]);
        async_copy16(Bbase + (size_t)row * KDIM + lcol,
                     &lB[0][chunk * 512 + lane * 8]);
    }

    for (int k0 = 0; k0 < KDIM; k0 += BK) {
        const int cur = (k0 >> 5) & 1;
        __syncthreads();   // drains stage(k0) async writes; prior frag reads done

        if (k0 + BK < KDIM) {   // stage next tile into the other buffer
            const int nxt = cur ^ 1;
            const int kn  = k0 + BK;
            const int c   = kn >> 10;        // 0..3: which patch of the 2x2
            const int d0  = kn & 1023;       // offset inside the 1024-ch block
#pragma unroll
            for (int r = 0; r < 2; ++r) {
                int chunk = wave * 2 + r;
                int row   = chunk * 16 + lrow;
                int fr = abase[r] + ((c & 2) ? awp[r] : 0) + (c & 1);
                async_copy16(A + (((size_t)fr) << 10) + d0 + lcol,
                             &lA[nxt][chunk * 512 + lane * 8]);
                async_copy16(Bbase + (size_t)row * KDIM + kn + lcol,
                             &lB[nxt][chunk * 512 + lane * 8]);
            }
        }

        bf16x8 af[4], bfr[4];
#pragma unroll
        for (int a = 0; a < 4; ++a) {
            af[a]  = *(const bf16x8*)&lA[cur][(wm + a * 16 + mrow) * BK + kq];
            bfr[a] = *(const bf16x8*)&lB[cur][(wn + a * 16 + mrow) * BK + kq];
        }
#pragma unroll
        for (int a = 0; a < 4; ++a)
#pragma unroll
            for (int b = 0; b < 4; ++b)
                acc[a][b] = __builtin_amdgcn_mfma_f32_16x16x32_bf16(af[a], bfr[b], acc[a][b], 0, 0, 0);
        // no second barrier: next iter's barrier orders buffer reuse
    }

    // epilogue: C/D layout col=lane&15, row=(lane>>4)*4+reg
    const int col   = lane & 15;
    const int rquad = (lane >> 4) * 4;
#pragma unroll
    for (int a = 0; a < 4; ++a) {
        int gm0 = bm * BM + wm + a * 16 + rquad;
#pragma unroll
        for (int b = 0; b < 4; ++b) {
            int gn = bn * BN + wn + b * 16 + col;
#pragma unroll
            for (int rg = 0; rg < 4; ++rg) {
                int gm = gm0 + rg;
                if (gm < MTOK) C[(size_t)gm * NOUT + gn] = acc[a][b][rg];
            }
        }
    }
}

// ---- fallback (ws too small): exact fp32, slow but correct ----
__global__ __launch_bounds__(256) void naive_fb(const float* __restrict__ feats,
                                                const float* __restrict__ W,
                                                float* __restrict__ out) {
    int t = blockIdx.x;
    int o = blockIdx.y * 256 + threadIdx.x;
    int im = 0;
    while (t >= c_mend[im]) im++;
    int r = t - c_moff[im];
    int wp = c_wp[im], wp2 = wp >> 1;
    int i = r / wp2, j = r - i * wp2;
    const float* f00 = feats + (size_t)(c_foff[im] + (2*i)*wp + 2*j) * 1024;
    const float* f10 = f00 + (size_t)wp * 1024;
    const float* w = W + (size_t)o * 4096;
    float s = 0.f;
    for (int d = 0; d < 1024; ++d)
        s += f00[d] * w[d*4] + f00[d+1024] * w[d*4+1] + f10[d] * w[d*4+2] + f10[d+1024] * w[d*4+3];
    out[(size_t)t * 1024 + o] = s;
}

extern "C" void kernel_launch(void* const* d_in, const int* in_sizes, int n_in,
                              void* d_out, int out_size, void* d_ws, size_t ws_size,
                              hipStream_t stream) {
    const float* feats = (const float*)d_in[0];   // [67440, 1024] fp32
    const float* W     = (const float*)d_in[1];   // [1024, 4096] fp32
    float* out         = (float*)d_out;           // [16860, 1024] fp32

    const size_t need = ((size_t)NTOK * 1024 + (size_t)NOUT * KDIM) * sizeof(unsigned short); // ~147 MB
    if (ws_size >= need) {
        unsigned short* featsbf = (unsigned short*)d_ws;                 // [67440, 1024] bf16
        unsigned short* Wb      = featsbf + (size_t)NTOK * 1024;         // [1024, 4096] bf16 (K-permuted)
        cast_feats<<<dim3(NTOK * 1024 / (256 * 8)), 256, 0, stream>>>(feats, featsbf);
        cast_w_perm<<<dim3(NOUT * 1024 / 256), 256, 0, stream>>>(W, Wb);
        gemm_fused<<<dim3(NOUT / BN, NBM), 256, 0, stream>>>(featsbf, Wb, out);
    } else {
        naive_fb<<<dim3(MTOK, 4), 256, 0, stream>>>(feats, W, out);
    }
}

// Round 2
// 611.348 us; speedup vs baseline: 1.1861x; 1.1861x over previous
//
#include <hip/hip_runtime.h>
#include <hip/hip_bf16.h>

// ---- static problem geometry (from reference: IMAGE_SIZES // 14) ----
// hp x wp per image: (110,110)(80,110)(110,64)(56,90)(108,108)(110,80)(64,64)(90,110)
// token counts: 12100 8800 7040 5040 11664 8800 4096 9900  -> 67440
// merged (n/4): 3025 2200 1760 1260 2916 2200 1024 2475    -> 16860
#define MTOK  16860
#define NTOK  67440
#define NOUT  1024
#define KDIM  4096
#define NBM   132      // ceil(16860/128) -> padded M = 16896
#define KTILES 64      // KDIM / 64

__device__ __constant__ int c_mend[8] = {3025,5225,6985,8245,11161,13361,14385,16860};
__device__ __constant__ int c_moff[8] = {0,3025,5225,6985,8245,11161,13361,14385};
__device__ __constant__ int c_foff[8] = {0,12100,20900,27940,32980,44644,53444,57540};
__device__ __constant__ int c_wp[8]   = {110,110,64,90,108,80,64,110};

typedef __attribute__((ext_vector_type(8))) short          bf16x8;  // 8 bf16 = 4 VGPRs
typedef __attribute__((ext_vector_type(8))) unsigned short u16x8;
typedef __attribute__((ext_vector_type(4))) float          f32x4;

__device__ __forceinline__ unsigned short f2bf(float f) {
    unsigned int u = __float_as_uint(f);
    u += 0x7FFFu + ((u >> 16) & 1u);   // round-to-nearest-even
    return (unsigned short)(u >> 16);
}

__device__ __forceinline__ void async_copy16(const void* g, void* l) {
    __builtin_amdgcn_global_load_lds(
        (const __attribute__((address_space(1))) void*)g,
        (__attribute__((address_space(3))) void*)l, 16, 0, 0);
}

// ---- kernel 1: fused pre-pass (one launch) ----
// blocks [0, 33720): verbatim fp32->bf16 cast of feats (streaming).
// blocks [33720, 37816): weight cast with K-permutation kappa' = c*1024 + d.
#define CF_BLOCKS 33720
__global__ __launch_bounds__(256) void cast_all(const float* __restrict__ feats,
                                                const float* __restrict__ W,
                                                unsigned short* __restrict__ fb,
                                                unsigned short* __restrict__ Wb) {
    int b = blockIdx.x;
    if (b < CF_BLOCKS) {
        size_t g = ((size_t)b * 256 + threadIdx.x) * 8;
        float4 a = *(const float4*)(feats + g);
        float4 c = *(const float4*)(feats + g + 4);
        u16x8 v;
        v[0]=f2bf(a.x); v[1]=f2bf(a.y); v[2]=f2bf(a.z); v[3]=f2bf(a.w);
        v[4]=f2bf(c.x); v[5]=f2bf(c.y); v[6]=f2bf(c.z); v[7]=f2bf(c.w);
        *(u16x8*)(fb + g) = v;
    } else {
        int g = (b - CF_BLOCKS) * 256 + threadIdx.x;   // 0 .. 1024*1024-1
        int n = g >> 10, d = g & 1023;
        float4 v = *(const float4*)(W + (size_t)n * 4096 + d * 4);
        unsigned short* o = Wb + (size_t)n * 4096 + d;
        o[0]    = f2bf(v.x);   // c=0 (ki=0,kj=0)
        o[1024] = f2bf(v.y);   // c=1 (ki=0,kj=1)
        o[2048] = f2bf(v.z);   // c=2 (ki=1,kj=0)
        o[3072] = f2bf(v.w);   // c=3 (ki=1,kj=1)
    }
}

// ---- kernel 2: fused merge+GEMM, counted-vmcnt schedule ----
// BK=64, LDS dbuf 2x(16K+16K)=64KiB -> 2 blocks/CU. Depth-2 tile prefetch:
// tile t's loads are drained by "s_waitcnt vmcnt(8)" (never 0 in steady state);
// tile t+2 is staged into buf[t&1] after barrier 2 proves all reads done.
// T2 swizzle: LDS byte ^= ((row&7)<<4), applied as pre-swizzled per-lane global
// SOURCE (linear LDS dest for global_load_lds) + same XOR on ds_read address.
__global__ __launch_bounds__(256, 2) void gemm_fused(const unsigned short* __restrict__ A,
                                                     const unsigned short* __restrict__ B,
                                                     float* __restrict__ C) {
    __shared__ unsigned short lA[2][128 * 64];   // 2 x 16 KiB
    __shared__ unsigned short lB[2][128 * 64];   // 2 x 16 KiB

    // bijective XCD swizzle: grid = 1056 = 8 XCDs * 132 chunks
    const int orig    = blockIdx.y * 8 + blockIdx.x;
    const int logical = (orig & 7) * NBM + (orig >> 3);
    const int bn = logical & 7;          // 0..7
    const int bm = logical >> 3;         // 0..131

    const int tid  = threadIdx.x;
    const int wave = tid >> 6, lane = tid & 63;
    const int wm = (wave >> 1) * 64, wn = (wave & 1) * 64;

    // staging thread constants: 4 instrs x 32 rows, 8 threads/row (16B chunks)
    const int srow = tid >> 3;                    // 0..31 (row within 32-row group)
    const int sp   = tid & 7;                     // 16B chunk index within row
    const int ssw  = (sp ^ (srow & 7)) * 8;       // swizzled source elem offset
    const int sdst = srow * 64 + sp * 8;          // linear LDS elem offset

    // per-thread A gather metadata for rows i*32 + srow
    int fbase[4], fwp[4];
#pragma unroll
    for (int i = 0; i < 4; ++i) {
        int t = bm * 128 + i * 32 + srow;
        if (t >= MTOK) t = 0;            // pad rows: read valid garbage, store masked
        int im = 0;
        while (t >= c_mend[im]) im++;
        int rr  = t - c_moff[im];
        int wp  = c_wp[im];
        int wp2 = wp >> 1;
        int ii = rr / wp2, jj = rr - ii * wp2;
        fbase[i] = c_foff[im] + 2 * ii * wp + 2 * jj;  // feats row of patch (ki=0,kj=0)
        fwp[i]   = wp;
    }
    const unsigned short* Bb = B + (size_t)(bn * 128) * KDIM;

    // stage one K-tile (64 cols): 4 A loads + 4 B loads per thread (16B each)
    auto stage = [&](int kt, int buf) {
        const int k0 = kt * 64;
        const int c  = k0 >> 10;         // which patch of the 2x2 (BK=64 | 1024)
        const int dA = (k0 & 1023) + ssw;
#pragma unroll
        for (int i = 0; i < 4; ++i) {
            int fr = fbase[i] + ((c & 2) ? fwp[i] : 0) + (c & 1);
            async_copy16(A + (((size_t)fr) << 10) + dA, &lA[buf][i * 2048 + sdst]);
        }
#pragma unroll
        for (int i = 0; i < 4; ++i) {
            async_copy16(Bb + (size_t)(i * 32 + srow) * KDIM + k0 + ssw,
                         &lB[buf][i * 2048 + sdst]);
        }
    };

    f32x4 acc[4][4];
#pragma unroll
    for (int a = 0; a < 4; ++a)
#pragma unroll
        for (int b = 0; b < 4; ++b) acc[a][b] = (f32x4){0.f, 0.f, 0.f, 0.f};

    const int mrow = lane & 15;
    const int q8   = (lane >> 4) * 8;
    const int rsw  = (mrow & 7) * 8;     // ds_read swizzle (row&7 == mrow&7 for all frags)

    // prologue: tiles 0 and 1 in flight (16 loads/thread outstanding)
    stage(0, 0);
    stage(1, 1);

#pragma unroll 2
    for (int kt = 0; kt < KTILES; ++kt) {
        const int cur = kt & 1;
        if (kt < KTILES - 1) {
            asm volatile("s_waitcnt vmcnt(8)" ::: "memory");   // drain tile kt only
        } else {
            asm volatile("s_waitcnt vmcnt(0)" ::: "memory");   // last tile: full drain
        }
        __builtin_amdgcn_s_barrier();          // all threads' tile-kt data visible
        __builtin_amdgcn_sched_barrier(0);

        bf16x8 af[2][4], bfr[2][4];
#pragma unroll
        for (int ks = 0; ks < 2; ++ks) {
            const int col = (ks * 32 + q8) ^ rsw;
#pragma unroll
            for (int a = 0; a < 4; ++a) {
                af[ks][a]  = *(const bf16x8*)&lA[cur][(wm + a * 16 + mrow) * 64 + col];
                bfr[ks][a] = *(const bf16x8*)&lB[cur][(wn + a * 16 + mrow) * 64 + col];
            }
        }
        __builtin_amdgcn_s_setprio(1);
#pragma unroll
        for (int ks = 0; ks < 2; ++ks)
#pragma unroll
            for (int a = 0; a < 4; ++a)
#pragma unroll
                for (int b = 0; b < 4; ++b)
                    acc[a][b] = __builtin_amdgcn_mfma_f32_16x16x32_bf16(af[ks][a], bfr[ks][b],
                                                                        acc[a][b], 0, 0, 0);
        __builtin_amdgcn_s_setprio(0);
        __builtin_amdgcn_sched_barrier(0);
        __builtin_amdgcn_s_barrier();          // all waves done reading buf[cur]
        if (kt + 2 < KTILES) stage(kt + 2, cur);   // refill freed buffer
    }

    // epilogue: C/D layout col=lane&15, row=(lane>>4)*4+reg
    const int col   = lane & 15;
    const int rquad = (lane >> 4) * 4;
#pragma unroll
    for (int a = 0; a < 4; ++a) {
        int gm0 = bm * 128 + wm + a * 16 + rquad;
#pragma unroll
        for (int b = 0; b < 4; ++b) {
            int gn = bn * 128 + wn + b * 16 + col;
#pragma unroll
            for (int rg = 0; rg < 4; ++rg) {
                int gm = gm0 + rg;
                if (gm < MTOK) C[(size_t)gm * NOUT + gn] = acc[a][b][rg];
            }
        }
    }
}

// ---- fallback (ws too small): exact fp32, slow but correct ----
__global__ __launch_bounds__(256) void naive_fb(const float* __restrict__ feats,
                                                const float* __restrict__ W,
                                                float* __restrict__ out) {
    int t = blockIdx.x;
    int o = blockIdx.y * 256 + threadIdx.x;
    int im = 0;
    while (t >= c_mend[im]) im++;
    int r = t - c_moff[im];
    int wp = c_wp[im], wp2 = wp >> 1;
    int i = r / wp2, j = r - i * wp2;
    const float* f00 = feats + (size_t)(c_foff[im] + (2*i)*wp + 2*j) * 1024;
    const float* f10 = f00 + (size_t)wp * 1024;
    const float* w = W + (size_t)o * 4096;
    float s = 0.f;
    for (int d = 0; d < 1024; ++d)
        s += f00[d] * w[d*4] + f00[d+1024] * w[d*4+1] + f10[d] * w[d*4+2] + f10[d+1024] * w[d*4+3];
    out[(size_t)t * 1024 + o] = s;
}

extern "C" void kernel_launch(void* const* d_in, const int* in_sizes, int n_in,
                              void* d_out, int out_size, void* d_ws, size_t ws_size,
                              hipStream_t stream) {
    const float* feats = (const float*)d_in[0];   // [67440, 1024] fp32
    const float* W     = (const float*)d_in[1];   // [1024, 4096] fp32
    float* out         = (float*)d_out;           // [16860, 1024] fp32

    const size_t need = ((size_t)NTOK * 1024 + (size_t)NOUT * KDIM) * sizeof(unsigned short); // ~147 MB
    if (ws_size >= need) {
        unsigned short* featsbf = (unsigned short*)d_ws;                 // [67440, 1024] bf16
        unsigned short* Wb      = featsbf + (size_t)NTOK * 1024;         // [1024, 4096] bf16 (K-permuted)
        cast_all<<<dim3(CF_BLOCKS + 4096), 256, 0, stream>>>(feats, W, featsbf, Wb);
        gemm_fused<<<dim3(NOUT / 128, NBM), 256, 0, stream>>>(featsbf, Wb, out);
    } else {
        naive_fb<<<dim3(MTOK, 4), 256, 0, stream>>>(feats, W, out);
    }
}

// Round 3
// 604.266 us; speedup vs baseline: 1.2000x; 1.0117x over previous
//
#include <hip/hip_runtime.h>
#include <hip/hip_bf16.h>

// ---- static problem geometry (from reference: IMAGE_SIZES // 14) ----
// hp x wp per image: (110,110)(80,110)(110,64)(56,90)(108,108)(110,80)(64,64)(90,110)
// token counts: 12100 8800 7040 5040 11664 8800 4096 9900  -> 67440
// merged (n/4): 3025 2200 1760 1260 2916 2200 1024 2475    -> 16860
#define MTOK  16860
#define NTOK  67440
#define NOUT  1024
#define KDIM  4096
#define NBM   132      // ceil(16860/128) -> padded M = 16896
#define KTILES 64      // KDIM / 64

__device__ __constant__ int c_mend[8] = {3025,5225,6985,8245,11161,13361,14385,16860};
__device__ __constant__ int c_moff[8] = {0,3025,5225,6985,8245,11161,13361,14385};
__device__ __constant__ int c_foff[8] = {0,12100,20900,27940,32980,44644,53444,57540};
__device__ __constant__ int c_wp[8]   = {110,110,64,90,108,80,64,110};

typedef __attribute__((ext_vector_type(8))) short          bf16x8;  // 8 bf16 = 4 VGPRs
typedef __attribute__((ext_vector_type(8))) unsigned short u16x8;
typedef __attribute__((ext_vector_type(4))) float          f32x4;

#define VMCNT(n) asm volatile("s_waitcnt vmcnt(" #n ")" ::: "memory")
#define LGKM0()  asm volatile("s_waitcnt lgkmcnt(0)" ::: "memory")

__device__ __forceinline__ unsigned short f2bf(float f) {
    unsigned int u = __float_as_uint(f);
    u += 0x7FFFu + ((u >> 16) & 1u);   // round-to-nearest-even
    return (unsigned short)(u >> 16);
}

// packed fp32x2 -> bf16x2 (RNE hardware cvt; same rounding as f2bf)
__device__ __forceinline__ unsigned int pkbf(float lo, float hi) {
    unsigned int r;
    asm("v_cvt_pk_bf16_f32 %0, %1, %2" : "=v"(r) : "v"(lo), "v"(hi));
    return r;
}

__device__ __forceinline__ void async_copy16(const void* g, void* l) {
    __builtin_amdgcn_global_load_lds(
        (const __attribute__((address_space(1))) void*)g,
        (__attribute__((address_space(3))) void*)l, 16, 0, 0);
}

// ---- kernel 1: weight fp32 -> bf16 with K-permutation (16 MB read, ~5 us) ----
// kappa' = c*1024 + d  (c = 2*ki+kj), so Wb[n][c*1024+d] = W[n][4d+c].
__global__ __launch_bounds__(256) void cast_w_perm(const float* __restrict__ W,
                                                   unsigned short* __restrict__ Wb) {
    int g = blockIdx.x * 256 + threadIdx.x;   // 0 .. 1024*1024-1
    int n = g >> 10, d = g & 1023;
    float4 v = *(const float4*)(W + (size_t)n * 4096 + d * 4);
    unsigned short* o = Wb + (size_t)n * 4096 + d;
    o[0]    = f2bf(v.x);   // c=0 (ki=0,kj=0)
    o[1024] = f2bf(v.y);   // c=1 (ki=0,kj=1)
    o[2048] = f2bf(v.z);   // c=2 (ki=1,kj=0)
    o[3072] = f2bf(v.w);   // c=3 (ki=1,kj=1)
}

// ---- kernel 2: single fused merge + cast + GEMM ----
// A[t][c*1024+d] = bf16(feats32[frow(t,c)][d]) staged via registers (fp32 load,
// v_cvt_pk_bf16_f32, swizzled ds_write_b128). B staged via global_load_lds from
// permuted bf16 weights. One barrier per K-tile; counted vmcnt (never 0 mid-loop):
//   entry invariant of phase t: buf[cur]=tile t ready; A(t+1) 8 loads in flight
//   (older); B(t+1) 4 glds in flight (newer).  vmcnt(4)=A arrived, vmcnt(8)=B landed.
__global__ __launch_bounds__(256, 2) void gemm_direct(const float* __restrict__ F,
                                                      const unsigned short* __restrict__ B,
                                                      float* __restrict__ C) {
    __shared__ unsigned short lA[2][128 * 64];   // 2 x 16 KiB
    __shared__ unsigned short lB[2][128 * 64];   // 2 x 16 KiB

    // bijective XCD swizzle: grid = 1056 = 8 XCDs * 132 chunks
    const int orig    = blockIdx.y * 8 + blockIdx.x;
    const int logical = (orig & 7) * NBM + (orig >> 3);
    const int bn = logical & 7;          // 0..7
    const int bm = logical >> 3;         // 0..131

    const int tid  = threadIdx.x;
    const int wave = tid >> 6, lane = tid & 63;
    const int wm = (wave >> 1) * 64, wn = (wave & 1) * 64;

    // staging thread constants: srow = row-within-32-group, sp = 16B-chunk idx
    const int srow = tid >> 3;                    // 0..31
    const int sp   = tid & 7;                     // 0..7
    const int sw   = srow & 7;                    // row-XOR swizzle key
    const int bssw = (sp ^ sw) * 8;               // B: pre-swizzled global src elems
    const int sdst = srow * 64 + sp * 8;          // B: linear LDS dest (lane-ordered)

    // per-thread A gather metadata for rows i*32 + srow
    int fbase[4], fwp[4];
#pragma unroll
    for (int i = 0; i < 4; ++i) {
        int t = bm * 128 + i * 32 + srow;
        if (t >= MTOK) t = 0;            // pad rows: read valid garbage, store masked
        int im = 0;
        while (t >= c_mend[im]) im++;
        int rr  = t - c_moff[im];
        int wp  = c_wp[im];
        int wp2 = wp >> 1;
        int ii = rr / wp2, jj = rr - ii * wp2;
        fbase[i] = c_foff[im] + 2 * ii * wp + 2 * jj;  // feats row of patch (ki=0,kj=0)
        fwp[i]   = wp;
    }
    const unsigned short* Bb = B + (size_t)(bn * 128) * KDIM;

    // issue 8 fp32 A-loads (32 floats = this thread's 4 rows x one bf16 chunk)
    auto issueA = [&](int t, float4* rg) {
        const int k0 = t * 64;
        const int c  = k0 >> 10;
        const int dA = (k0 & 1023) + sp * 8;
#pragma unroll
        for (int i = 0; i < 4; ++i) {
            int fr = fbase[i] + ((c & 2) ? fwp[i] : 0) + (c & 1);
            const float* src = F + (((size_t)fr) << 10) + dA;
            rg[2 * i]     = *(const float4*)(src);
            rg[2 * i + 1] = *(const float4*)(src + 4);
        }
    };
    // convert + swizzled LDS write: global chunk sp stored at LDS chunk sp^(row&7)
    auto writeA = [&](float4* rg, int buf) {
#pragma unroll
        for (int i = 0; i < 4; ++i) {
            float4 x = rg[2 * i], y = rg[2 * i + 1];
            uint4 v;
            v.x = pkbf(x.x, x.y); v.y = pkbf(x.z, x.w);
            v.z = pkbf(y.x, y.y); v.w = pkbf(y.z, y.w);
            *(uint4*)&lA[buf][(i * 32 + srow) * 64 + ((sp ^ sw) * 8)] = v;
        }
    };
    auto issueB = [&](int t, int buf) {
        const int k0 = t * 64;
#pragma unroll
        for (int i = 0; i < 4; ++i)
            async_copy16(Bb + (size_t)(i * 32 + srow) * KDIM + k0 + bssw,
                         &lB[buf][i * 2048 + sdst]);
    };

    f32x4 acc[4][4];
#pragma unroll
    for (int a = 0; a < 4; ++a)
#pragma unroll
        for (int b = 0; b < 4; ++b) acc[a][b] = (f32x4){0.f, 0.f, 0.f, 0.f};

    const int mrow = lane & 15;
    const int q8   = (lane >> 4) * 8;
    const int rsw  = (mrow & 7) * 8;     // ds_read swizzle

    auto frag_mfma = [&](int cur) {
        bf16x8 af[2][4], bfr[2][4];
#pragma unroll
        for (int ks = 0; ks < 2; ++ks) {
            const int col = (ks * 32 + q8) ^ rsw;
#pragma unroll
            for (int a = 0; a < 4; ++a) {
                af[ks][a]  = *(const bf16x8*)&lA[cur][(wm + a * 16 + mrow) * 64 + col];
                bfr[ks][a] = *(const bf16x8*)&lB[cur][(wn + a * 16 + mrow) * 64 + col];
            }
        }
        __builtin_amdgcn_s_setprio(1);
#pragma unroll
        for (int ks = 0; ks < 2; ++ks)
#pragma unroll
            for (int a = 0; a < 4; ++a)
#pragma unroll
                for (int b = 0; b < 4; ++b)
                    acc[a][b] = __builtin_amdgcn_mfma_f32_16x16x32_bf16(af[ks][a], bfr[ks][b],
                                                                        acc[a][b], 0, 0, 0);
        __builtin_amdgcn_s_setprio(0);
    };

    float4 r1[8], r2[8];

    // ---- prologue ----
    issueA(0, r1);                       // vm: A0[8]
    issueB(0, 0);                        // vm: A0[8] + B0[4]
    VMCNT(4);                            // A0 arrived
    writeA(r1, 0);
    issueA(1, r2);                       // vm: B0[4] + A1[8]
    VMCNT(8);                            // B0 landed
    LGKM0();
    __builtin_amdgcn_sched_barrier(0);
    __builtin_amdgcn_s_barrier();        // buf[0] complete
    issueB(1, 1);                        // vm: A1[8] + B1[4]

    // ---- main loop: phases 0..61 (two per iteration) ----
#pragma unroll 1
    for (int kt = 0; kt < 62; kt += 2) {
        // phase kt (cur=0): consume r2 = A(kt+1)
        frag_mfma(0);
        VMCNT(4);                        // A(kt+1) arrived
        writeA(r2, 1);
        issueA(kt + 2, r1);              // vm: B(kt+1)[4] + A(kt+2)[8]
        VMCNT(8);                        // B(kt+1) landed
        LGKM0();
        __builtin_amdgcn_sched_barrier(0);
        __builtin_amdgcn_s_barrier();    // buf[1] complete
        issueB(kt + 2, 0);

        // phase kt+1 (cur=1): consume r1 = A(kt+2)
        frag_mfma(1);
        VMCNT(4);
        writeA(r1, 0);
        issueA(kt + 3, r2);
        VMCNT(8);
        LGKM0();
        __builtin_amdgcn_sched_barrier(0);
        __builtin_amdgcn_s_barrier();    // buf[0] complete
        issueB(kt + 3, 1);
    }

    // ---- phase 62 (cur=0): r2 = A(63) in flight, B(63)->buf[1] in flight ----
    frag_mfma(0);
    VMCNT(4);
    writeA(r2, 1);
    VMCNT(0);                            // B(63) landed
    LGKM0();
    __builtin_amdgcn_sched_barrier(0);
    __builtin_amdgcn_s_barrier();        // buf[1] complete
    // ---- phase 63 (cur=1) ----
    frag_mfma(1);

    // epilogue: C/D layout col=lane&15, row=(lane>>4)*4+reg
    const int col   = lane & 15;
    const int rquad = (lane >> 4) * 4;
#pragma unroll
    for (int a = 0; a < 4; ++a) {
        int gm0 = bm * 128 + wm + a * 16 + rquad;
#pragma unroll
        for (int b = 0; b < 4; ++b) {
            int gn = bn * 128 + wn + b * 16 + col;
#pragma unroll
            for (int rg = 0; rg < 4; ++rg) {
                int gm = gm0 + rg;
                if (gm < MTOK) C[(size_t)gm * NOUT + gn] = acc[a][b][rg];
            }
        }
    }
}

// ---- fallback (ws too small): exact fp32, slow but correct ----
__global__ __launch_bounds__(256) void naive_fb(const float* __restrict__ feats,
                                                const float* __restrict__ W,
                                                float* __restrict__ out) {
    int t = blockIdx.x;
    int o = blockIdx.y * 256 + threadIdx.x;
    int im = 0;
    while (t >= c_mend[im]) im++;
    int r = t - c_moff[im];
    int wp = c_wp[im], wp2 = wp >> 1;
    int i = r / wp2, j = r - i * wp2;
    const float* f00 = feats + (size_t)(c_foff[im] + (2*i)*wp + 2*j) * 1024;
    const float* f10 = f00 + (size_t)wp * 1024;
    const float* w = W + (size_t)o * 4096;
    float s = 0.f;
    for (int d = 0; d < 1024; ++d)
        s += f00[d] * w[d*4] + f00[d+1024] * w[d*4+1] + f10[d] * w[d*4+2] + f10[d+1024] * w[d*4+3];
    out[(size_t)t * 1024 + o] = s;
}

extern "C" void kernel_launch(void* const* d_in, const int* in_sizes, int n_in,
                              void* d_out, int out_size, void* d_ws, size_t ws_size,
                              hipStream_t stream) {
    const float* feats = (const float*)d_in[0];   // [67440, 1024] fp32
    const float* W     = (const float*)d_in[1];   // [1024, 4096] fp32
    float* out         = (float*)d_out;           // [16860, 1024] fp32

    const size_t need = (size_t)NOUT * KDIM * sizeof(unsigned short);  // 8 MB
    if (ws_size >= need) {
        unsigned short* Wb = (unsigned short*)d_ws;   // [1024, 4096] bf16 (K-permuted)
        cast_w_perm<<<dim3(4096), 256, 0, stream>>>(W, Wb);
        gemm_direct<<<dim3(8, NBM), 256, 0, stream>>>(feats, Wb, out);
    } else {
        naive_fb<<<dim3(MTOK, 4), 256, 0, stream>>>(feats, W, out);
    }
}

// Round 4
// 590.754 us; speedup vs baseline: 1.2275x; 1.0229x over previous
//
#include <hip/hip_runtime.h>
#include <hip/hip_bf16.h>

// ---- static problem geometry (from reference: IMAGE_SIZES // 14) ----
// hp x wp per image: (110,110)(80,110)(110,64)(56,90)(108,108)(110,80)(64,64)(90,110)
// token counts: 12100 8800 7040 5040 11664 8800 4096 9900  -> 67440
// merged (n/4): 3025 2200 1760 1260 2916 2200 1024 2475    -> 16860
#define MTOK  16860
#define NTOK  67440
#define NOUT  1024
#define KDIM  4096
#define NBM   132      // ceil(16860/128) -> padded M = 16896
#define KTILES 64      // KDIM / 64

__device__ __constant__ int c_mend[8] = {3025,5225,6985,8245,11161,13361,14385,16860};
__device__ __constant__ int c_moff[8] = {0,3025,5225,6985,8245,11161,13361,14385};
__device__ __constant__ int c_foff[8] = {0,12100,20900,27940,32980,44644,53444,57540};
__device__ __constant__ int c_wp[8]   = {110,110,64,90,108,80,64,110};

typedef __attribute__((ext_vector_type(8))) short          bf16x8;  // 8 bf16 = 4 VGPRs
typedef __attribute__((ext_vector_type(8))) unsigned short u16x8;
typedef __attribute__((ext_vector_type(4))) float          f32x4;

#define VMCNT(n) asm volatile("s_waitcnt vmcnt(" #n ")" ::: "memory")
#define LGKM0()  asm volatile("s_waitcnt lgkmcnt(0)" ::: "memory")

__device__ __forceinline__ unsigned short f2bf(float f) {
    unsigned int u = __float_as_uint(f);
    u += 0x7FFFu + ((u >> 16) & 1u);   // round-to-nearest-even
    return (unsigned short)(u >> 16);
}

// packed fp32x2 -> bf16x2 (RNE hardware cvt; same rounding as f2bf)
__device__ __forceinline__ unsigned int pkbf(float lo, float hi) {
    unsigned int r;
    asm("v_cvt_pk_bf16_f32 %0, %1, %2" : "=v"(r) : "v"(lo), "v"(hi));
    return r;
}

__device__ __forceinline__ void async_copy16(const void* g, void* l) {
    __builtin_amdgcn_global_load_lds(
        (const __attribute__((address_space(1))) void*)g,
        (__attribute__((address_space(3))) void*)l, 16, 0, 0);
}

// ---- kernel 1: weight fp32 -> bf16 with K-permutation (16 MB read, ~5 us) ----
// kappa' = c*1024 + d  (c = 2*ki+kj), so Wb[n][c*1024+d] = W[n][4d+c].
__global__ __launch_bounds__(256) void cast_w_perm(const float* __restrict__ W,
                                                   unsigned short* __restrict__ Wb) {
    int g = blockIdx.x * 256 + threadIdx.x;   // 0 .. 1024*1024-1
    int n = g >> 10, d = g & 1023;
    float4 v = *(const float4*)(W + (size_t)n * 4096 + d * 4);
    unsigned short* o = Wb + (size_t)n * 4096 + d;
    o[0]    = f2bf(v.x);   // c=0 (ki=0,kj=0)
    o[1024] = f2bf(v.y);   // c=1 (ki=0,kj=1)
    o[2048] = f2bf(v.z);   // c=2 (ki=1,kj=0)
    o[3072] = f2bf(v.w);   // c=3 (ki=1,kj=1)
}

// ---- kernel 2: single fused merge + cast + GEMM, depth-2 on BOTH operands ----
// Per-phase schedule (tile t):
//   issueA(t+2)                                  [A now has ~2-phase flight]
//   ds_read ks=0 frags ; MFMA ks=0 (16)
//   vmcnt(12): A(t+1) regs arrived (leaves B(t+1)*4 + A(t+2)*8)
//   ds_read ks=1 frags ; cvt+swizzled ds_write A(t+1) -> buf^1
//   MFMA ks=1 (16)                               [hides the ds_writes]
//   vmcnt(8): B(t+1) global_load_lds landed (leaves A(t+2)*8)
//   lgkmcnt(0) ; s_barrier                       [buf^1 = tile t+1 complete]
//   issueB(t+2) -> buf (just consumed)
__global__ __launch_bounds__(256, 2) void gemm_direct(const float* __restrict__ F,
                                                      const unsigned short* __restrict__ B,
                                                      float* __restrict__ C) {
    __shared__ unsigned short lA[2][128 * 64];   // 2 x 16 KiB
    __shared__ unsigned short lB[2][128 * 64];   // 2 x 16 KiB

    // bijective XCD swizzle: grid = 1056 = 8 XCDs * 132 chunks
    const int orig    = blockIdx.y * 8 + blockIdx.x;
    const int logical = (orig & 7) * NBM + (orig >> 3);
    const int bn = logical & 7;          // 0..7
    const int bm = logical >> 3;         // 0..131

    const int tid  = threadIdx.x;
    const int wave = tid >> 6, lane = tid & 63;
    const int wm = (wave >> 1) * 64, wn = (wave & 1) * 64;

    // staging thread constants: srow = row-within-32-group, sp = 16B-chunk idx
    const int srow = tid >> 3;                    // 0..31
    const int sp   = tid & 7;                     // 0..7
    const int sw   = srow & 7;                    // row-XOR swizzle key
    const int bssw = (sp ^ sw) * 8;               // B: pre-swizzled global src elems
    const int sdst = srow * 64 + sp * 8;          // B: linear LDS dest (lane-ordered)

    // per-thread A gather metadata for rows i*32 + srow
    int fbase[4], fwp[4];
#pragma unroll
    for (int i = 0; i < 4; ++i) {
        int t = bm * 128 + i * 32 + srow;
        if (t >= MTOK) t = 0;            // pad rows: read valid garbage, store masked
        int im = 0;
        while (t >= c_mend[im]) im++;
        int rr  = t - c_moff[im];
        int wp  = c_wp[im];
        int wp2 = wp >> 1;
        int ii = rr / wp2, jj = rr - ii * wp2;
        fbase[i] = c_foff[im] + 2 * ii * wp + 2 * jj;  // feats row of patch (ki=0,kj=0)
        fwp[i]   = wp;
    }
    const unsigned short* Bb = B + (size_t)(bn * 128) * KDIM;

    // issue 8 fp32 A-loads (this thread's 4 rows x one 32B fp32 chunk)
    auto issueA = [&](int t, float4 (&rg)[8]) {
        const int k0 = t * 64;
        const int c  = k0 >> 10;
        const int dA = (k0 & 1023) + sp * 8;
#pragma unroll
        for (int i = 0; i < 4; ++i) {
            int fr = fbase[i] + ((c & 2) ? fwp[i] : 0) + (c & 1);
            const float* src = F + (((size_t)fr) << 10) + dA;
            rg[2 * i]     = *(const float4*)(src);
            rg[2 * i + 1] = *(const float4*)(src + 4);
        }
    };
    // convert + swizzled LDS write: global chunk sp stored at LDS chunk sp^(row&7)
    auto writeA = [&](float4 (&rg)[8], int buf) {
#pragma unroll
        for (int i = 0; i < 4; ++i) {
            float4 x = rg[2 * i], y = rg[2 * i + 1];
            uint4 v;
            v.x = pkbf(x.x, x.y); v.y = pkbf(x.z, x.w);
            v.z = pkbf(y.x, y.y); v.w = pkbf(y.z, y.w);
            *(uint4*)&lA[buf][(i * 32 + srow) * 64 + ((sp ^ sw) * 8)] = v;
        }
    };
    auto issueB = [&](int t, int buf) {
        const int k0 = t * 64;
#pragma unroll
        for (int i = 0; i < 4; ++i)
            async_copy16(Bb + (size_t)(i * 32 + srow) * KDIM + k0 + bssw,
                         &lB[buf][i * 2048 + sdst]);
    };

    f32x4 acc[4][4];
#pragma unroll
    for (int a = 0; a < 4; ++a)
#pragma unroll
        for (int b = 0; b < 4; ++b) acc[a][b] = (f32x4){0.f, 0.f, 0.f, 0.f};

    const int mrow = lane & 15;
    const int q8   = (lane >> 4) * 8;
    const int rsw  = (mrow & 15 & 7) * 8;   // ds_read swizzle (row&7 == mrow&7)

    auto reads_half = [&](int cur, int ks, bf16x8 (&af)[4], bf16x8 (&bf_)[4]) {
        const int col = (ks * 32 + q8) ^ rsw;
#pragma unroll
        for (int a = 0; a < 4; ++a) {
            af[a]  = *(const bf16x8*)&lA[cur][(wm + a * 16 + mrow) * 64 + col];
            bf_[a] = *(const bf16x8*)&lB[cur][(wn + a * 16 + mrow) * 64 + col];
        }
    };
    auto mfma_half = [&](bf16x8 (&af)[4], bf16x8 (&bf_)[4]) {
        __builtin_amdgcn_s_setprio(1);
#pragma unroll
        for (int a = 0; a < 4; ++a)
#pragma unroll
            for (int b = 0; b < 4; ++b)
                acc[a][b] = __builtin_amdgcn_mfma_f32_16x16x32_bf16(af[a], bf_[b],
                                                                    acc[a][b], 0, 0, 0);
        __builtin_amdgcn_s_setprio(0);
    };

    float4 rT0[8], rT1[8];

    // ---- prologue ----
    issueA(0, rT0);                      // vm: A0*8
    issueB(0, 0);                        // vm: A0*8 + B0*4
    issueA(1, rT1);                      // vm: A0*8 + B0*4 + A1*8 = 20
    VMCNT(12);                           // A0 arrived
    writeA(rT0, 0);
    VMCNT(8);                            // B0 landed (leaves A1*8)
    LGKM0();
    __builtin_amdgcn_sched_barrier(0);
    __builtin_amdgcn_s_barrier();        // buf0 = tile 0 complete
    __builtin_amdgcn_sched_barrier(0);
    issueB(1, 1);                        // vm: A1*8 + B1*4

    auto phase_steady = [&](int cur, float4 (&rIss)[8], float4 (&rWr)[8], int ktNext) {
        issueA(ktNext, rIss);            // vm: A(t+1)*8 + B(t+1)*4 + A(t+2)*8
        bf16x8 a0[4], b0[4];
        reads_half(cur, 0, a0, b0);
        mfma_half(a0, b0);
        VMCNT(12);                       // A(t+1) arrived
        bf16x8 a1[4], b1[4];
        reads_half(cur, 1, a1, b1);
        writeA(rWr, cur ^ 1);
        __builtin_amdgcn_sched_barrier(0);
        mfma_half(a1, b1);               // hides the ds_writes
        VMCNT(8);                        // B(t+1) landed (leaves A(t+2)*8)
        LGKM0();
        __builtin_amdgcn_sched_barrier(0);
        __builtin_amdgcn_s_barrier();    // buf[cur^1] = tile t+1 complete
        __builtin_amdgcn_sched_barrier(0);
        issueB(ktNext, cur);             // refill just-consumed buffer
    };

    // ---- main loop: phases 0..61 (two per iteration) ----
#pragma unroll 1
    for (int kt = 0; kt < 62; kt += 2) {
        phase_steady(0, rT0, rT1, kt + 2);   // consume buf0; rT1=A(kt+1)->buf1
        phase_steady(1, rT1, rT0, kt + 3);   // consume buf1; rT0=A(kt+2)->buf0
    }

    // ---- phase 62 (cur=0): rT1 = A(63) in flight, B(63)->buf1 in flight ----
    {
        bf16x8 a0[4], b0[4];
        reads_half(0, 0, a0, b0);
        mfma_half(a0, b0);
        VMCNT(4);                        // A(63) arrived (leaves B(63)*4)
        bf16x8 a1[4], b1[4];
        reads_half(0, 1, a1, b1);
        writeA(rT1, 1);
        __builtin_amdgcn_sched_barrier(0);
        mfma_half(a1, b1);
        VMCNT(0);                        // B(63) landed
        LGKM0();
        __builtin_amdgcn_sched_barrier(0);
        __builtin_amdgcn_s_barrier();    // buf1 = tile 63 complete
    }
    // ---- phase 63 (cur=1) ----
    {
        bf16x8 a0[4], b0[4];
        reads_half(1, 0, a0, b0);
        mfma_half(a0, b0);
        bf16x8 a1[4], b1[4];
        reads_half(1, 1, a1, b1);
        mfma_half(a1, b1);
    }

    // epilogue: C/D layout col=lane&15, row=(lane>>4)*4+reg
    const int col   = lane & 15;
    const int rquad = (lane >> 4) * 4;
#pragma unroll
    for (int a = 0; a < 4; ++a) {
        int gm0 = bm * 128 + wm + a * 16 + rquad;
#pragma unroll
        for (int b = 0; b < 4; ++b) {
            int gn = bn * 128 + wn + b * 16 + col;
#pragma unroll
            for (int rg = 0; rg < 4; ++rg) {
                int gm = gm0 + rg;
                if (gm < MTOK) C[(size_t)gm * NOUT + gn] = acc[a][b][rg];
            }
        }
    }
}

// ---- fallback (ws too small): exact fp32, slow but correct ----
__global__ __launch_bounds__(256) void naive_fb(const float* __restrict__ feats,
                                                const float* __restrict__ W,
                                                float* __restrict__ out) {
    int t = blockIdx.x;
    int o = blockIdx.y * 256 + threadIdx.x;
    int im = 0;
    while (t >= c_mend[im]) im++;
    int r = t - c_moff[im];
    int wp = c_wp[im], wp2 = wp >> 1;
    int i = r / wp2, j = r - i * wp2;
    const float* f00 = feats + (size_t)(c_foff[im] + (2*i)*wp + 2*j) * 1024;
    const float* f10 = f00 + (size_t)wp * 1024;
    const float* w = W + (size_t)o * 4096;
    float s = 0.f;
    for (int d = 0; d < 1024; ++d)
        s += f00[d] * w[d*4] + f00[d+1024] * w[d*4+1] + f10[d] * w[d*4+2] + f10[d+1024] * w[d*4+3];
    out[(size_t)t * 1024 + o] = s;
}

extern "C" void kernel_launch(void* const* d_in, const int* in_sizes, int n_in,
                              void* d_out, int out_size, void* d_ws, size_t ws_size,
                              hipStream_t stream) {
    const float* feats = (const float*)d_in[0];   // [67440, 1024] fp32
    const float* W     = (const float*)d_in[1];   // [1024, 4096] fp32
    float* out         = (float*)d_out;           // [16860, 1024] fp32

    const size_t need = (size_t)NOUT * KDIM * sizeof(unsigned short);  // 8 MB
    if (ws_size >= need) {
        unsigned short* Wb = (unsigned short*)d_ws;   // [1024, 4096] bf16 (K-permuted)
        cast_w_perm<<<dim3(4096), 256, 0, stream>>>(W, Wb);
        gemm_direct<<<dim3(8, NBM), 256, 0, stream>>>(feats, Wb, out);
    } else {
        naive_fb<<<dim3(MTOK, 4), 256, 0, stream>>>(feats, W, out);
    }
}